// Round 9
// baseline (336.349 us; speedup 1.0000x reference)
//
#include <hip/hip_runtime.h>
#include <hip/hip_bf16.h>
#include <math.h>

#define BB 16
#define SS 512
#define DMM 256
#define HH 8
#define DFF 32
#define KIDX 5

// ---------------------------------------------------------------------------
// GEMM: Y = X @ W^T + bias. X:(M,256), W:(256,256) row-major (N,K).
// TM x TN tile, 256 threads (16x16), per-thread (GM*4)x(GN*4) in split-4
// fragment groups. BK=16, reg prefetch. K accumulated sequentially 0..255.
// ---------------------------------------------------------------------------
template<int TM, int TN, int GM, int GN, bool HEADS>
__device__ __forceinline__ void gemm_body(
    const float* __restrict__ X, const float* __restrict__ W,
    const float* __restrict__ bias, float* __restrict__ Y)
{
  __shared__ float As[16][TM];
  __shared__ float Bs[16][TN];
  constexpr int NA = TM / 64;
  constexpr int NB = TN / 64;
  const int tid = threadIdx.x;
  const int tx = tid & 15;
  const int ty = tid >> 4;
  const int m0 = blockIdx.x * TM;
  const int n0 = blockIdx.y * TN;

  float4 pa[NA], pb[NB];
  #pragma unroll
  for (int i = 0; i < NA; ++i) {
    const int f = tid * NA + i;
    pa[i] = *reinterpret_cast<const float4*>(&X[(size_t)(m0 + (f >> 2)) * DMM + ((f & 3) << 2)]);
  }
  #pragma unroll
  for (int i = 0; i < NB; ++i) {
    const int f = tid * NB + i;
    pb[i] = *reinterpret_cast<const float4*>(&W[(size_t)(n0 + (f >> 2)) * DMM + ((f & 3) << 2)]);
  }

  float acc[GM * 4][GN * 4] = {};

  for (int k0 = 0; k0 < DMM; k0 += 16) {
    #pragma unroll
    for (int i = 0; i < NA; ++i) {
      const int f = tid * NA + i;
      const int r = f >> 2, c4 = (f & 3) << 2;
      As[c4 + 0][r] = pa[i].x; As[c4 + 1][r] = pa[i].y;
      As[c4 + 2][r] = pa[i].z; As[c4 + 3][r] = pa[i].w;
    }
    #pragma unroll
    for (int i = 0; i < NB; ++i) {
      const int f = tid * NB + i;
      const int r = f >> 2, c4 = (f & 3) << 2;
      Bs[c4 + 0][r] = pb[i].x; Bs[c4 + 1][r] = pb[i].y;
      Bs[c4 + 2][r] = pb[i].z; Bs[c4 + 3][r] = pb[i].w;
    }
    __syncthreads();
    if (k0 + 16 < DMM) {
      #pragma unroll
      for (int i = 0; i < NA; ++i) {
        const int f = tid * NA + i;
        pa[i] = *reinterpret_cast<const float4*>(&X[(size_t)(m0 + (f >> 2)) * DMM + k0 + 16 + ((f & 3) << 2)]);
      }
      #pragma unroll
      for (int i = 0; i < NB; ++i) {
        const int f = tid * NB + i;
        pb[i] = *reinterpret_cast<const float4*>(&W[(size_t)(n0 + (f >> 2)) * DMM + k0 + 16 + ((f & 3) << 2)]);
      }
    }
    #pragma unroll
    for (int kk = 0; kk < 16; ++kk) {
      float4 af[GM], bf[GN];
      #pragma unroll
      for (int gm = 0; gm < GM; ++gm)
        af[gm] = *reinterpret_cast<const float4*>(&As[kk][gm * (TM / 2) + ty * 4]);
      #pragma unroll
      for (int gn = 0; gn < GN; ++gn)
        bf[gn] = *reinterpret_cast<const float4*>(&Bs[kk][gn * (TN / 2) + tx * 4]);
      #pragma unroll
      for (int gm = 0; gm < GM; ++gm) {
        const float am[4] = {af[gm].x, af[gm].y, af[gm].z, af[gm].w};
        #pragma unroll
        for (int i = 0; i < 4; ++i) {
          #pragma unroll
          for (int gn = 0; gn < GN; ++gn) {
            acc[gm*4+i][gn*4+0] = fmaf(am[i], bf[gn].x, acc[gm*4+i][gn*4+0]);
            acc[gm*4+i][gn*4+1] = fmaf(am[i], bf[gn].y, acc[gm*4+i][gn*4+1]);
            acc[gm*4+i][gn*4+2] = fmaf(am[i], bf[gn].z, acc[gm*4+i][gn*4+2]);
            acc[gm*4+i][gn*4+3] = fmaf(am[i], bf[gn].w, acc[gm*4+i][gn*4+3]);
          }
        }
      }
    }
    __syncthreads();
  }

  #pragma unroll
  for (int gn = 0; gn < GN; ++gn) {
    const int n = n0 + gn * (TN / 2) + tx * 4;
    const float4 b4 = *reinterpret_cast<const float4*>(&bias[n]);
    #pragma unroll
    for (int gm = 0; gm < GM; ++gm) {
      #pragma unroll
      for (int i = 0; i < 4; ++i) {
        const int m = m0 + gm * (TM / 2) + ty * 4 + i;
        float4 o;
        o.x = acc[gm*4+i][gn*4+0] + b4.x;
        o.y = acc[gm*4+i][gn*4+1] + b4.y;
        o.z = acc[gm*4+i][gn*4+2] + b4.z;
        o.w = acc[gm*4+i][gn*4+3] + b4.w;
        if (HEADS) {
          const int bb = m >> 9;
          const int s  = m & (SS - 1);
          const int hh = n >> 5;
          const int d  = n & (DFF - 1);
          *reinterpret_cast<float4*>(&Y[(((size_t)bb * HH + hh) * SS + s) * DFF + d]) = o;
        } else {
          *reinterpret_cast<float4*>(&Y[(size_t)m * DMM + n]) = o;
        }
      }
    }
  }
}

// q/k/v projections + attn-matrix zero-fill in one launch.
// z in {0,1,2}: GEMM (q and k both use Wk). z==3: zero the attn region
// (134 MB float4 memset, overlaps the GEMM slices; stream-ordered before
// attn_kernel's sparse writes).
__global__ __launch_bounds__(256) void proj_kernel(
    const float* __restrict__ q, const float* __restrict__ k, const float* __restrict__ v,
    const float* __restrict__ Wk, const float* __restrict__ bk,
    const float* __restrict__ Wv, const float* __restrict__ bv,
    float* __restrict__ qh, float* __restrict__ kh, float* __restrict__ vh,
    float* __restrict__ attnp)
{
  const int z = blockIdx.z;
  if (z == 3) {
    const int blk = blockIdx.y * 64 + blockIdx.x;       // 0..127
    float4* dst = reinterpret_cast<float4*>(attnp) + (size_t)blk * 65536;
    const float4 zero = {0.f, 0.f, 0.f, 0.f};
    #pragma unroll 4
    for (int i = threadIdx.x; i < 65536; i += 256) dst[i] = zero;
    return;
  }
  const float* X = (z == 0) ? q : (z == 1) ? k : v;
  const float* W = (z == 2) ? Wv : Wk;
  const float* bias = (z == 2) ? bv : bk;
  float* Y = (z == 0) ? qh : (z == 1) ? kh : vh;
  gemm_body<128, 128, 2, 2, true>(X, W, bias, Y);
}

__global__ __launch_bounds__(256) void out_kernel(
    const float* __restrict__ X, const float* __restrict__ Wo,
    const float* __restrict__ bo, float* __restrict__ Y)
{
  gemm_body<128, 64, 2, 1, false>(X, Wo, bo, Y);
}

// ---------------------------------------------------------------------------
// Attention row tail: softmax, top-5 (Batcher sort-8 + order-statistic
// butterfly merge of sorted-5 lists), re-softmax, zero_pad, SPARSE attn
// writes (zeros pre-filled by proj z==3), sparse PV gather.
// Math/order identical to the passing Round-5 version.
// ---------------------------------------------------------------------------
__device__ __forceinline__ void attn_row_tail(
    float* p, const int qrow, const int lane,
    const int b, const int h, const int bh,
    const int* __restrict__ zp,
    float* __restrict__ attn, float* __restrict__ concat,
    const float* __restrict__ vb,
    float* wsw, int* wsc)
{
  const int ncols = qrow + 1;

  float m = p[0];
  #pragma unroll
  for (int s2 = 1; s2 < 8; ++s2) m = fmaxf(m, p[s2]);
  #pragma unroll
  for (int off = 32; off >= 1; off >>= 1) m = fmaxf(m, __shfl_xor(m, off, 64));
  float sum = 0.f;
  #pragma unroll
  for (int s2 = 0; s2 < 8; ++s2) {
    const float e = (p[s2] == -INFINITY) ? 0.f : __expf(p[s2] - m);
    p[s2] = e;
    sum += e;
  }
  #pragma unroll
  for (int off = 32; off >= 1; off >>= 1) sum += __shfl_xor(sum, off, 64);
  const float inv = 1.0f / sum;
  #pragma unroll
  for (int s2 = 0; s2 < 8; ++s2) p[s2] *= inv;

  float neww[8];
  if (qrow > KIDX) {
    float v[8];
    #pragma unroll
    for (int s2 = 0; s2 < 8; ++s2) {
      const int col = lane + (s2 << 6);
      v[s2] = (col < ncols) ? p[s2] : -INFINITY;
    }
    #define CE(i, j) { const float t = fmaxf(v[i], v[j]); v[j] = fminf(v[i], v[j]); v[i] = t; }
    CE(0,1) CE(2,3) CE(4,5) CE(6,7)
    CE(0,2) CE(1,3) CE(4,6) CE(5,7)
    CE(1,2) CE(5,6)
    CE(0,4) CE(1,5) CE(2,6) CE(3,7)
    CE(2,4) CE(3,5)
    CE(1,2) CE(3,4) CE(5,6)
    #undef CE
    float a0 = v[0], a1 = v[1], a2 = v[2], a3 = v[3], a4 = v[4];
    #pragma unroll
    for (int off = 1; off <= 32; off <<= 1) {
      const float b0 = __shfl_xor(a0, off, 64);
      const float b1 = __shfl_xor(a1, off, 64);
      const float b2 = __shfl_xor(a2, off, 64);
      const float b3 = __shfl_xor(a3, off, 64);
      const float b4 = __shfl_xor(a4, off, 64);
      const float n0 = fmaxf(a0, b0);
      const float n1 = fmaxf(fmaxf(a1, b1), fminf(a0, b0));
      const float n2 = fmaxf(fmaxf(a2, b2), fmaxf(fminf(a0, b1), fminf(a1, b0)));
      const float n3 = fmaxf(fmaxf(a3, b3),
                       fmaxf(fmaxf(fminf(a0, b2), fminf(a1, b1)), fminf(a2, b0)));
      const float n4 = fmaxf(fmaxf(a4, b4),
                       fmaxf(fmaxf(fminf(a0, b3), fminf(a1, b2)),
                             fmaxf(fminf(a2, b1), fminf(a3, b0))));
      a0 = n0; a1 = n1; a2 = n2; a3 = n3; a4 = n4;
    }
    const float m1 = a0;
    const float thr = a4;
    float nsum = 0.f;
    #pragma unroll
    for (int s2 = 0; s2 < 8; ++s2) {
      const int col = lane + (s2 << 6);
      float e = 0.f;
      if (col < ncols && (p[s2] - thr >= 0.f)) e = __expf(p[s2] - m1);
      neww[s2] = e;
      nsum += e;
    }
    #pragma unroll
    for (int off = 32; off >= 1; off >>= 1) nsum += __shfl_xor(nsum, off, 64);
    const float ninv = 1.0f / nsum;
    #pragma unroll
    for (int s2 = 0; s2 < 8; ++s2) neww[s2] *= ninv;
  } else {
    #pragma unroll
    for (int s2 = 0; s2 < 8; ++s2) neww[s2] = p[s2];
  }

  if (qrow == 0 && *zp != 0) {
    #pragma unroll
    for (int s2 = 0; s2 < 8; ++s2) neww[s2] = 0.f;
  }

  // SPARSE attn writes (zeros already filled by proj z==3 pass)
  {
    float* arow = attn + ((size_t)bh * SS + qrow) * SS;
    if (qrow <= KIDX) {
      if (lane < ncols) arow[lane] = neww[0];
    } else {
      #pragma unroll
      for (int s2 = 0; s2 < 8; ++s2)
        if (neww[s2] != 0.f) arow[lane + (s2 << 6)] = neww[s2];
    }
  }

  // PV: rank kept columns into per-wave LDS, then parallel loads
  {
    unsigned long long msks[8];
    #pragma unroll
    for (int s2 = 0; s2 < 8; ++s2) msks[s2] = __ballot(neww[s2] != 0.f);
    int rbase = 0;
    #pragma unroll
    for (int s2 = 0; s2 < 8; ++s2) {
      const unsigned long long msk = msks[s2];
      const int myr = rbase + __popcll(msk & ((1ull << lane) - 1ull));
      if (((msk >> lane) & 1ull) && myr < 8) {
        wsw[myr] = neww[s2];
        wsc[myr] = (s2 << 6) | lane;
      }
      rbase += __popcll(msk);
    }
    const int nk = rbase;
    if (lane < 8 && lane >= nk) { wsw[lane] = 0.f; wsc[lane] = 0; }

    const int dd = lane & 31;
    float accv = 0.f;
    if (nk <= 8) {
      #pragma unroll
      for (int i = 0; i < 8; ++i)
        accv += wsw[i] * vb[(size_t)wsc[i] * DFF + dd];
    } else {
      // tie-overflow fallback (practically never taken)
      #pragma unroll
      for (int s2 = 0; s2 < 8; ++s2) {
        unsigned long long msk = msks[s2];
        while (msk) {
          const int src = __ffsll(msk) - 1;
          msk &= msk - 1;
          accv += __shfl(neww[s2], src, 64) * vb[(size_t)(src + (s2 << 6)) * DFF + dd];
        }
      }
    }
    if (lane < 32)
      concat[((size_t)b * SS + qrow) * DMM + h * DFF + dd] = accv;
  }
}

// ---------------------------------------------------------------------------
// Attention: block = 4 waves x 2 rows = 8 consecutive qrows of one (b,h).
// Wave w handles rows base+w and base+w+4 (same chunk range). Each staged
// K chunk b128-read ONCE per lane feeds BOTH rows' dot products. K chunk in
// LDS as [col][granule] with rotation swizzle phys_g=(g+col)&7 (same
// bijection write & read). Heavy row-groups launch first (index reversed).
// ---------------------------------------------------------------------------
__global__ __launch_bounds__(256) void attn_kernel(
    const float* __restrict__ qh,
    const float* __restrict__ kh,
    const float* __restrict__ vh,
    const int* __restrict__ zp,
    float* __restrict__ attn,
    float* __restrict__ concat)
{
  __shared__ float4 Ksh[64 * 8];     // [col][granule], swizzled
  __shared__ float ws_w[4][8];
  __shared__ int   ws_c[4][8];

  const int tid  = threadIdx.x;
  const int lane = tid & 63;
  const int wave = tid >> 6;
  const int grp  = blockIdx.x;        // 0..8191
  const int bh   = grp >> 6;          // 64 row-groups of 8 per (b,h)
  const int base = ((grp & 63) ^ 63) << 3;   // heavy groups first
  const int rA   = base + wave;
  const int rB   = rA + 4;
  const int b    = bh >> 3;
  const int h    = bh & 7;
  const float scale = 0.17677669529663688f;  // 1/sqrt(32)

  const float* kb = kh + (size_t)bh * SS * DFF;
  const float* vb = vh + (size_t)bh * SS * DFF;

  float4 qA[8], qB[8];
  {
    const float* qpA = qh + ((size_t)bh * SS + rA) * DFF;
    const float* qpB = qh + ((size_t)bh * SS + rB) * DFF;
    #pragma unroll
    for (int g = 0; g < 8; ++g) {
      qA[g] = *reinterpret_cast<const float4*>(qpA + g * 4);
      qB[g] = *reinterpret_cast<const float4*>(qpB + g * 4);
    }
  }

  // rows base..base+7 share the same last chunk (base % 8 == 0)
  const int nch = (base >> 6) + 1;

  const int scol = tid & 63;
  const int g0   = (tid >> 6) << 1;

  float pA[8], pB[8];
  #pragma unroll
  for (int i = 0; i < 8; ++i) { pA[i] = -INFINITY; pB[i] = -INFINITY; }

  const float* kp0 = kb + (size_t)scol * DFF + g0 * 4;
  float4 r0 = *reinterpret_cast<const float4*>(kp0);
  float4 r1 = *reinterpret_cast<const float4*>(kp0 + 4);

  for (int c = 0; c < nch; ++c) {
    Ksh[(scol << 3) + ((g0 + scol) & 7)]     = r0;
    Ksh[(scol << 3) + ((g0 + 1 + scol) & 7)] = r1;
    __syncthreads();
    if (c + 1 < nch) {
      const float* kp = kb + (size_t)(((c + 1) << 6) + scol) * DFF + g0 * 4;
      r0 = *reinterpret_cast<const float4*>(kp);
      r1 = *reinterpret_cast<const float4*>(kp + 4);
    }
    {
      const int col = (c << 6) + lane;
      float d0A = 0.f, d1A = 0.f, d0B = 0.f, d1B = 0.f;
      #pragma unroll
      for (int g = 0; g < 8; ++g) {
        const float4 kv = Ksh[(lane << 3) + ((g + lane) & 7)];
        const float4 qa = qA[g];
        const float4 qb = qB[g];
        d0A = fmaf(qa.x, kv.x, d0A);
        d1A = fmaf(qa.y, kv.y, d1A);
        d0A = fmaf(qa.z, kv.z, d0A);
        d1A = fmaf(qa.w, kv.w, d1A);
        d0B = fmaf(qb.x, kv.x, d0B);
        d1B = fmaf(qb.y, kv.y, d1B);
        d0B = fmaf(qb.z, kv.z, d0B);
        d1B = fmaf(qb.w, kv.w, d1B);
      }
      if (col <= rA) pA[c] = (d0A + d1A) * scale;
      if (col <= rB) pB[c] = (d0B + d1B) * scale;
    }
    __syncthreads();
  }

  attn_row_tail(pA, rA, lane, b, h, bh, zp, attn, concat, vb, ws_w[wave], ws_c[wave]);
  attn_row_tail(pB, rB, lane, b, h, bh, zp, attn, concat, vb, ws_w[wave], ws_c[wave]);
}

extern "C" void kernel_launch(void* const* d_in, const int* in_sizes, int n_in,
                              void* d_out, int out_size, void* d_ws, size_t ws_size,
                              hipStream_t stream) {
  const float* q  = (const float*)d_in[0];
  const float* k  = (const float*)d_in[1];
  const float* v  = (const float*)d_in[2];
  const int*   zp = (const int*)d_in[4];
  const float* Wk = (const float*)d_in[5];
  const float* bk = (const float*)d_in[6];
  const float* Wv = (const float*)d_in[7];
  const float* bv = (const float*)d_in[8];
  const float* Wo = (const float*)d_in[9];
  const float* bo = (const float*)d_in[10];

  float* ws     = (float*)d_ws;
  float* qhp    = ws;                 // (B,H,S,DF)
  float* khp    = ws + 2097152;       // (B,H,S,DF)
  float* vhp    = ws + 4194304;       // (B,H,S,DF)
  float* concat = ws + 6291456;       // (B,S,DM)

  float* outp  = (float*)d_out;                       // (B,S,DM)
  float* attnp = outp + (size_t)BB * SS * DMM;        // (B,H,S,S)

  proj_kernel<<<dim3(64, 2, 4), 256, 0, stream>>>(q, k, v, Wk, bk, Wv, bv, qhp, khp, vhp, attnp);
  attn_kernel<<<dim3(BB * HH * SS / 8), 256, 0, stream>>>(qhp, khp, vhp, zp, attnp, concat);
  out_kernel<<<dim3(64, 4), 256, 0, stream>>>(concat, Wo, bo, outp);
}